// Round 1
// baseline (430.599 us; speedup 1.0000x reference)
//
#include <hip/hip_runtime.h>

// ComplexScaling: separable bilinear resample, NHWC [N,H,W,2] fp32.
// out[n,i,j,c] = wy0*(wx0*in[n,y0,x0,c] + wx1*in[n,y0,x1,c])
//              + wy1*(wx0*in[n,y1,x0,c] + wx1*in[n,y1,x1,c])
// with zeros-padding masks folded into the wx/wy weights.

__global__ __launch_bounds__(256) void ComplexScaling_kernel(
    const float* __restrict__ in, const float* __restrict__ theta,
    float* __restrict__ out, int N, int H, int W) {
  const float s = 1.0f + theta[0];

  const int W2 = W >> 1;                       // 2 pixels per thread
  long long tid = (long long)blockIdx.x * blockDim.x + threadIdx.x;
  long long total = (long long)N * H * W2;
  if (tid >= total) return;

  int j2 = (int)(tid % W2);
  long long r = tid / W2;
  int i = (int)(r % H);
  int n = (int)(r / H);
  int j = j2 << 1;

  // ---- row (y) coordinate: shared by both pixels ----
  float yn  = (2.0f * (float)i + 1.0f) / (float)H - 1.0f;
  float iy  = ((s * yn + 1.0f) * (float)H - 1.0f) * 0.5f;
  float fy0 = floorf(iy);
  float wy1 = iy - fy0;
  float wy0 = 1.0f - wy1;
  float fy1 = fy0 + 1.0f;
  float Hm1 = (float)(H - 1);
  float my0 = (fy0 >= 0.0f && fy0 <= Hm1) ? 1.0f : 0.0f;
  float my1 = (fy1 >= 0.0f && fy1 <= Hm1) ? 1.0f : 0.0f;
  wy0 *= my0;
  wy1 *= my1;
  int y0 = (int)fminf(fmaxf(fy0, 0.0f), Hm1);
  int y1 = (int)fminf(fmaxf(fy1, 0.0f), Hm1);

  const float* __restrict__ row0 = in + (((long long)n * H + y0) * W) * 2;
  const float* __restrict__ row1 = in + (((long long)n * H + y1) * W) * 2;

  float Wm1 = (float)(W - 1);
  float4 result;

  #pragma unroll
  for (int p = 0; p < 2; ++p) {
    int jj = j + p;
    // ---- column (x) coordinate ----
    float xn  = (2.0f * (float)jj + 1.0f) / (float)W - 1.0f;
    float ix  = ((s * xn + 1.0f) * (float)W - 1.0f) * 0.5f;
    float fx0 = floorf(ix);
    float wx1 = ix - fx0;
    float wx0 = 1.0f - wx1;
    float fx1 = fx0 + 1.0f;
    float mx0 = (fx0 >= 0.0f && fx0 <= Wm1) ? 1.0f : 0.0f;
    float mx1 = (fx1 >= 0.0f && fx1 <= Wm1) ? 1.0f : 0.0f;
    wx0 *= mx0;
    wx1 *= mx1;
    int x0 = (int)fminf(fmaxf(fx0, 0.0f), Wm1);
    int x1 = (int)fminf(fmaxf(fx1, 0.0f), Wm1);

    const float2 a00 = *(const float2*)(row0 + 2 * x0);
    const float2 a01 = *(const float2*)(row0 + 2 * x1);
    const float2 a10 = *(const float2*)(row1 + 2 * x0);
    const float2 a11 = *(const float2*)(row1 + 2 * x1);

    float vx = wy0 * (wx0 * a00.x + wx1 * a01.x) + wy1 * (wx0 * a10.x + wx1 * a11.x);
    float vy = wy0 * (wx0 * a00.y + wx1 * a01.y) + wy1 * (wx0 * a10.y + wx1 * a11.y);

    if (p == 0) { result.x = vx; result.y = vy; }
    else        { result.z = vx; result.w = vy; }
  }

  // out offset: ((n*H + i)*W + j)*2 ; j even -> multiple of 4 floats -> 16B aligned
  float* __restrict__ dst = out + (((long long)n * H + i) * W + j) * 2;
  *(float4*)dst = result;
}

extern "C" void kernel_launch(void* const* d_in, const int* in_sizes, int n_in,
                              void* d_out, int out_size, void* d_ws, size_t ws_size,
                              hipStream_t stream) {
  const float* in    = (const float*)d_in[0];
  const float* theta = (const float*)d_in[1];
  float* out = (float*)d_out;

  const int N = 32, H = 1024, W = 1024;
  long long total = (long long)N * H * (W / 2);  // threads (2 pixels each)
  int block = 256;
  long long grid = (total + block - 1) / block;
  ComplexScaling_kernel<<<(dim3)(unsigned)grid, block, 0, stream>>>(in, theta, out, N, H, W);
}